// Round 7
// baseline (306.248 us; speedup 1.0000x reference)
//
#include <hip/hip_runtime.h>
#include <stdint.h>

#define NNODES 50000
#define NEDGES 1600000
#define HID 512
#define NEG_SLOPE 0.01f
#define NBUCK 98     // dst>>9 buckets (512 nodes each)
#define NBLK 200     // partition blocks
#define TILE 8000    // NEDGES / NBLK
#define NSUB 8       // agg sub-blocks per bucket
#define GPBLK 391    // ceil(50000/128) M-tiles
#define MROWS 50048  // padded rows in t0p

typedef __attribute__((ext_vector_type(8))) short bf16x8;
typedef __attribute__((ext_vector_type(8))) unsigned short u16x8;
typedef __attribute__((ext_vector_type(4))) float f32x4;

__device__ __forceinline__ float bf2f(unsigned short u) {
  unsigned int x = ((unsigned int)u) << 16;
  return __builtin_bit_cast(float, x);
}
__device__ __forceinline__ unsigned short f2bf(float f) {
  unsigned int u = __builtin_bit_cast(unsigned int, f);
  u += 0x7FFFu + ((u >> 16) & 1u);
  return (unsigned short)(u >> 16);
}
__device__ __forceinline__ void gload_lds16(const void* g, void* l) {
  __builtin_amdgcn_global_load_lds(
      (const __attribute__((address_space(1))) void*)g,
      (__attribute__((address_space(3))) void*)l, 16, 0, 0);
}

// ---- detect edge_index storage (int32 vs int64-as-u32-pairs) ----
__global__ void flagk(const int* __restrict__ ei, int* __restrict__ flag) {
  int t = threadIdx.x;
  unsigned long long m = __ballot(ei[2 * t + 1] != 0);
  if (t == 0) *flag = (m != 0ULL) ? 1 : 0;
}

// ---- per-block bucket histogram: hist[b*NBLK + blk] ----
__global__ __launch_bounds__(256) void histk(const int* __restrict__ ei,
                                             const int* __restrict__ flag,
                                             int* __restrict__ hist) {
  __shared__ int h[NBUCK];
  int t = threadIdx.x, blk = blockIdx.x;
  for (int i = t; i < NBUCK; i += 256) h[i] = 0;
  __syncthreads();
  int f = *flag;
  int e0 = blk * TILE;
  for (int e = e0 + 2 * t; e < e0 + TILE; e += 512) {
    int d0, d1;
    if (f) {
      int2 v = *reinterpret_cast<const int2*>(&ei[(size_t)NEDGES + e]);
      d0 = v.x; d1 = v.y;
    } else {
      int4 v = *reinterpret_cast<const int4*>(&ei[2 * ((size_t)NEDGES + e)]);
      d0 = v.x; d1 = v.z;
    }
    if ((unsigned)d0 < NNODES) atomicAdd(&h[d0 >> 9], 1);
    if ((unsigned)d1 < NNODES) atomicAdd(&h[d1 >> 9], 1);
  }
  __syncthreads();
  for (int i = t; i < NBUCK; i += 256) hist[i * NBLK + blk] = h[i];
}

// ---- single-block exclusive scan of hist (bucket-major) -> bases + bstart ----
__global__ __launch_bounds__(512) void scanh(int* __restrict__ hist,
                                             int* __restrict__ bstart) {
  __shared__ int s[512];
  const int TOT = NBUCK * NBLK;  // 19600
  const int C = 40;
  int t = threadIdx.x;
  int base = t * C;
  int sum = 0;
#pragma unroll
  for (int i = 0; i < C; i++) {
    int idx = base + i;
    sum += (idx < TOT) ? hist[idx] : 0;
  }
  s[t] = sum;
  __syncthreads();
  for (int off = 1; off < 512; off <<= 1) {
    int u = (t >= off) ? s[t - off] : 0;
    __syncthreads();
    s[t] += u;
    __syncthreads();
  }
  int run = (t > 0) ? s[t - 1] : 0;
#pragma unroll
  for (int i = 0; i < C; i++) {
    int idx = base + i;
    if (idx < TOT) {
      int v = hist[idx];
      hist[idx] = run;
      if (idx % NBLK == 0) bstart[idx / NBLK] = run;
      run += v;
    }
  }
  if (t == 511) bstart[NBUCK] = s[511];
}

// ---- bucketed scatter: packed (dst&511)<<16 | src, LDS-local positions ----
__global__ __launch_bounds__(256) void binscatter(const int* __restrict__ ei,
                                                  const int* __restrict__ flag,
                                                  const int* __restrict__ hbase,
                                                  unsigned int* __restrict__ pcol) {
  __shared__ int lb[NBUCK];
  int t = threadIdx.x, blk = blockIdx.x;
  for (int i = t; i < NBUCK; i += 256) lb[i] = hbase[i * NBLK + blk];
  __syncthreads();
  int f = *flag;
  int e0 = blk * TILE;
  for (int e = e0 + 2 * t; e < e0 + TILE; e += 512) {
    int s0, s1, d0, d1;
    if (f) {
      int2 vs = *reinterpret_cast<const int2*>(&ei[e]);
      int2 vd = *reinterpret_cast<const int2*>(&ei[(size_t)NEDGES + e]);
      s0 = vs.x; s1 = vs.y; d0 = vd.x; d1 = vd.y;
    } else {
      int4 vs = *reinterpret_cast<const int4*>(&ei[2 * (size_t)e]);
      int4 vd = *reinterpret_cast<const int4*>(&ei[2 * ((size_t)NEDGES + e)]);
      s0 = vs.x; s1 = vs.z; d0 = vd.x; d1 = vd.z;
    }
    if ((unsigned)d0 < NNODES) {
      if ((unsigned)s0 >= NNODES) s0 = 0;
      int pos = atomicAdd(&lb[d0 >> 9], 1);
      pcol[pos] = ((unsigned)(d0 & 511) << 16) | (unsigned)s0;
    }
    if ((unsigned)d1 < NNODES) {
      if ((unsigned)s1 >= NNODES) s1 = 0;
      int pos = atomicAdd(&lb[d1 >> 9], 1);
      pcol[pos] = ((unsigned)(d1 & 511) << 16) | (unsigned)s1;
    }
  }
}

// ---- Wt0[n][k] = bf16(W_in[k][n]) ----
__global__ void tcast(const float* __restrict__ w, unsigned short* __restrict__ wt) {
  int i = blockIdx.x * 256 + threadIdx.x;  // 262144
  int n = i >> 9, k = i & 511;
  wt[i] = f2bf(w[(k << 9) | n]);
}

// ---- wave-parallel 512-dot ----
__device__ __forceinline__ float wave_dot(const float* __restrict__ Arow,
                                          const float* __restrict__ B, int j) {
  int l = threadIdx.x & 63;
  float4 a0 = *reinterpret_cast<const float4*>(Arow + l * 8);
  float4 a1 = *reinterpret_cast<const float4*>(Arow + l * 8 + 4);
  const float* bb = B + (size_t)(l * 8) * 4 + j;
  float s = a0.x * bb[0] + a0.y * bb[4] + a0.z * bb[8] + a0.w * bb[12] +
            a1.x * bb[16] + a1.y * bb[20] + a1.z * bb[24] + a1.w * bb[28];
#pragma unroll
  for (int off = 1; off < 64; off <<= 1) s += __shfl_xor(s, off);
  return s;
}

__global__ __launch_bounds__(256) void smallA(
    const float* __restrict__ W2l, const float* __restrict__ W2r,
    const float* __restrict__ Wout, const float* __restrict__ b2l,
    const float* __restrict__ bout,
    float* __restrict__ Wlp, float* __restrict__ Wrp, float* __restrict__ bp) {
  int gw = blockIdx.x * 4 + (threadIdx.x >> 6);
  int l = threadIdx.x & 63;
  if (gw < 2048) {
    float v = wave_dot(W2l + (size_t)(gw >> 2) * 512, Wout, gw & 3);
    if (l == 0) Wlp[gw] = v;
  } else if (gw < 4096) {
    int g = gw - 2048;
    float v = wave_dot(W2r + (size_t)(g >> 2) * 512, Wout, g & 3);
    if (l == 0) Wrp[g] = v;
  } else if (gw < 4100) {
    int j = gw - 4096;
    float v = wave_dot(b2l, Wout, j);
    if (l == 0) bp[j] = v + bout[j];
  }
}

__global__ __launch_bounds__(256) void smallB(
    const float* __restrict__ W1l, const float* __restrict__ W1r,
    const float* __restrict__ b1l,
    const float* __restrict__ Wlp, const float* __restrict__ Wrp,
    const float* __restrict__ bp,
    float* __restrict__ Pall, float* __restrict__ kb, float* __restrict__ kc) {
  int gw = blockIdx.x * 4 + (threadIdx.x >> 6);
  int l = threadIdx.x & 63;
  if (gw < 6144) {
    int k = gw / 12, jg = gw % 12;
    int g = jg >> 2, j = jg & 3;
    float v;
    if (g == 0) v = wave_dot(W1l + (size_t)k * 512, Wlp, j);
    else if (g == 1) v = wave_dot(W1r + (size_t)k * 512, Wlp, j) +
                         wave_dot(W1l + (size_t)k * 512, Wrp, j);
    else v = wave_dot(W1r + (size_t)k * 512, Wrp, j);
    if (l == 0) Pall[k * 12 + jg] = v;
  } else if (gw < 6152) {
    int i = gw - 6144, j = i & 3;
    if (i < 4) {
      float v = wave_dot(b1l, Wlp, j);
      if (l == 0) kb[j] = v;
    } else {
      float v = wave_dot(b1l, Wrp, j);
      if (l == 0) kc[j] = v + bp[j];
    }
  }
}

// ---- fused GEMM1 + 12-col projection, m97 128x128 tile, N split 4-way ----
// x0 = leaky(feat@W_in + b_in) never materialized. Swapped-operand MFMA:
// acc[ni][mi] = mfma(bfr, af) -> lane holds rows (mi*16+r15), cols (ni*16+kl*4+rg).
// Projection in fp32 from acc; kl-reduce via shfl; wc-reduce via LDS; per-nb
// partial written to t0p[nb][MROWS][12].
__global__ __launch_bounds__(256) void gemmproj(
    const float* __restrict__ A, const unsigned short* __restrict__ Bt,
    const float* __restrict__ bias, const float* __restrict__ Pall,
    float* __restrict__ t0p) {
  __shared__ unsigned short As[128 * 32];
  __shared__ unsigned short Bs[128 * 32];
  __shared__ float tab[128 * 12];
  const int tid = threadIdx.x;
  const int wave = tid >> 6, lane = tid & 63;
  // swizzle: sibling N-blocks (same mt) share XCD slot (w%8 == mt%8)
  const int w = blockIdx.x;
  const int mt = (w & 7) + ((w >> 5) << 3);
  const int nb = (w >> 3) & 3;
  if (mt >= GPBLK) return;
  const int bm = mt * 128, bn = nb * 128;
  const int wr = wave >> 1, wc = wave & 1;
  const int r15 = lane & 15, kl = lane >> 4;
  const int srow = lane >> 2, soff = (lane & 3) * 8;

  for (int i = tid; i < 1536; i += 256) tab[i] = 0.f;

  f32x4 acc[4][4];  // [ni][mi]
#pragma unroll
  for (int i = 0; i < 4; i++)
#pragma unroll
    for (int j = 0; j < 4; j++) acc[i][j] = {0.f, 0.f, 0.f, 0.f};

  for (int kt = 0; kt < HID / 32; ++kt) {
    // B: async global->LDS (wave-uniform LDS base + lane*16B)
#pragma unroll
    for (int rr = 0; rr < 2; ++rr) {
      int c = wave * 2 + rr;
      int row = c * 16 + srow;
      gload_lds16(Bt + (size_t)(bn + row) * HID + kt * 32 + soff, (void*)&Bs[c * 512]);
    }
    // A: fp32 load -> bf16 pack -> LDS (2 slots of 8 elems per thread)
#pragma unroll
    for (int ss = 0; ss < 2; ++ss) {
      int s = tid + ss * 256;
      int row = s >> 2, k8 = (s & 3) * 8;
      int garow = bm + row;
      if (garow >= NNODES) garow = 0;  // pad rows: never consumed downstream
      const float* ga = A + (size_t)garow * HID + kt * 32 + k8;
      float4 v0 = *reinterpret_cast<const float4*>(ga);
      float4 v1 = *reinterpret_cast<const float4*>(ga + 4);
      u16x8 pk;
      pk[0] = f2bf(v0.x); pk[1] = f2bf(v0.y); pk[2] = f2bf(v0.z); pk[3] = f2bf(v0.w);
      pk[4] = f2bf(v1.x); pk[5] = f2bf(v1.y); pk[6] = f2bf(v1.z); pk[7] = f2bf(v1.w);
      *reinterpret_cast<u16x8*>(&As[row * 32 + k8]) = pk;
    }
    __syncthreads();
    bf16x8 af[4], bfr[4];
#pragma unroll
    for (int mi = 0; mi < 4; ++mi)
      af[mi] = *reinterpret_cast<const bf16x8*>(&As[(wr * 64 + mi * 16 + r15) * 32 + kl * 8]);
#pragma unroll
    for (int ni = 0; ni < 4; ++ni)
      bfr[ni] = *reinterpret_cast<const bf16x8*>(&Bs[(wc * 64 + ni * 16 + r15) * 32 + kl * 8]);
#pragma unroll
    for (int ni = 0; ni < 4; ++ni)
#pragma unroll
      for (int mi = 0; mi < 4; ++mi)
        acc[ni][mi] = __builtin_amdgcn_mfma_f32_16x16x32_bf16(bfr[ni], af[mi], acc[ni][mi], 0, 0, 0);
    __syncthreads();
  }

  // ---- projection epilogue (fp32, straight from acc) ----
  float part[4][12];
#pragma unroll
  for (int mi = 0; mi < 4; ++mi)
#pragma unroll
    for (int j = 0; j < 12; ++j) part[mi][j] = 0.f;

#pragma unroll
  for (int ni = 0; ni < 4; ++ni) {
    int nbase = bn + wc * 64 + ni * 16 + kl * 4;
    float4 bv4 = *reinterpret_cast<const float4*>(bias + nbase);
    float bb[4] = {bv4.x, bv4.y, bv4.z, bv4.w};
#pragma unroll
    for (int rg = 0; rg < 4; ++rg) {
      const float* Pc = Pall + (size_t)(nbase + rg) * 12;
      float4 p0 = *reinterpret_cast<const float4*>(Pc);
      float4 p1 = *reinterpret_cast<const float4*>(Pc + 4);
      float4 p2 = *reinterpret_cast<const float4*>(Pc + 8);
#pragma unroll
      for (int mi = 0; mi < 4; ++mi) {
        float v = acc[ni][mi][rg] + bb[rg];
        v = (v >= 0.f) ? v : NEG_SLOPE * v;
        part[mi][0] += v * p0.x; part[mi][1] += v * p0.y;
        part[mi][2] += v * p0.z; part[mi][3] += v * p0.w;
        part[mi][4] += v * p1.x; part[mi][5] += v * p1.y;
        part[mi][6] += v * p1.z; part[mi][7] += v * p1.w;
        part[mi][8] += v * p2.x; part[mi][9] += v * p2.y;
        part[mi][10] += v * p2.z; part[mi][11] += v * p2.w;
      }
    }
  }
#pragma unroll
  for (int mi = 0; mi < 4; ++mi)
#pragma unroll
    for (int j = 0; j < 12; ++j) {
      part[mi][j] += __shfl_xor(part[mi][j], 16);
      part[mi][j] += __shfl_xor(part[mi][j], 32);
    }
  if (kl == 0) {
#pragma unroll
    for (int mi = 0; mi < 4; ++mi) {
      int r = wr * 64 + mi * 16 + r15;
#pragma unroll
      for (int j = 0; j < 12; ++j) atomicAdd(&tab[r * 12 + j], part[mi][j]);
    }
  }
  __syncthreads();
  float* o = t0p + (size_t)nb * MROWS * 12 + (size_t)bm * 12;
  for (int i = tid; i < 1536; i += 256) o[i] = tab[i];
}

// ---- t0[n][12] = sum over nb partials ----
__global__ __launch_bounds__(256) void reduce_t0(const float* __restrict__ t0p,
                                                 float* __restrict__ t0) {
  int i = blockIdx.x * 256 + threadIdx.x;
  if (i >= NNODES * 12) return;
  const size_t S = (size_t)MROWS * 12;
  t0[i] = t0p[i] + t0p[S + i] + t0p[2 * S + i] + t0p[3 * S + i];
}

// ---- agg pass 1 (bucketed LDS accumulate): vals = t0a[src], + degree ----
__global__ __launch_bounds__(256) void aggA(
    const unsigned int* __restrict__ pcol, const int* __restrict__ bstart,
    const float* __restrict__ t0, float* __restrict__ partial) {
  __shared__ float tab[512 * 5];
  int t = threadIdx.x;
  int b = blockIdx.x >> 3, sb = blockIdx.x & 7;
  for (int i = t; i < 2560; i += 256) tab[i] = 0.f;
  __syncthreads();
  int st = bstart[b], en = bstart[b + 1];
  int len = en - st;
  int a0 = st + (int)(((long long)len * sb) >> 3);
  int a1 = st + (int)(((long long)len * (sb + 1)) >> 3);
  for (int e = a0 + t; e < a1; e += 256) {
    unsigned v = pcol[e];
    int i = v >> 16, src = v & 0xFFFF;
    float4 x = *reinterpret_cast<const float4*>(t0 + (size_t)src * 12);
    atomicAdd(&tab[i * 5 + 0], x.x);
    atomicAdd(&tab[i * 5 + 1], x.y);
    atomicAdd(&tab[i * 5 + 2], x.z);
    atomicAdd(&tab[i * 5 + 3], x.w);
    atomicAdd(&tab[i * 5 + 4], 1.f);
  }
  __syncthreads();
  float* o = partial + (size_t)blockIdx.x * 2560;
  for (int i = t; i < 2560; i += 256) o[i] = tab[i];
}

// ---- fin pass 1: s1[n] = sum/deg + t0b[n]; store deg ----
__global__ __launch_bounds__(256) void finA(
    const float* __restrict__ partial, const float* __restrict__ t0,
    float* __restrict__ s1, float* __restrict__ degf) {
  int n = blockIdx.x * 256 + threadIdx.x;
  if (n >= NNODES) return;
  int b = n >> 9, i = n & 511;
  float a[5] = {0.f, 0.f, 0.f, 0.f, 0.f};
#pragma unroll
  for (int s = 0; s < 8; s++) {
    const float* p = partial + (size_t)(b * 8 + s) * 2560 + i * 5;
#pragma unroll
    for (int j = 0; j < 5; j++) a[j] += p[j];
  }
  float deg = a[4];
  float sc = (deg > 0.f) ? 1.f / deg : 0.f;
  float4 tb = *reinterpret_cast<const float4*>(t0 + (size_t)n * 12 + 4);
  float4 o = {a[0] * sc + tb.x, a[1] * sc + tb.y, a[2] * sc + tb.z, a[3] * sc + tb.w};
  *reinterpret_cast<float4*>(s1 + (size_t)n * 4) = o;
  degf[n] = deg;
}

// ---- agg pass 2: vals = s1[src] ----
__global__ __launch_bounds__(256) void aggB(
    const unsigned int* __restrict__ pcol, const int* __restrict__ bstart,
    const float* __restrict__ s1, float* __restrict__ partial) {
  __shared__ float tab[512 * 4];
  int t = threadIdx.x;
  int b = blockIdx.x >> 3, sb = blockIdx.x & 7;
  for (int i = t; i < 2048; i += 256) tab[i] = 0.f;
  __syncthreads();
  int st = bstart[b], en = bstart[b + 1];
  int len = en - st;
  int a0 = st + (int)(((long long)len * sb) >> 3);
  int a1 = st + (int)(((long long)len * (sb + 1)) >> 3);
  for (int e = a0 + t; e < a1; e += 256) {
    unsigned v = pcol[e];
    int i = v >> 16, src = v & 0xFFFF;
    float4 x = *reinterpret_cast<const float4*>(s1 + (size_t)src * 4);
    atomicAdd(&tab[i * 4 + 0], x.x);
    atomicAdd(&tab[i * 4 + 1], x.y);
    atomicAdd(&tab[i * 4 + 2], x.z);
    atomicAdd(&tab[i * 4 + 3], x.w);
  }
  __syncthreads();
  float* o = partial + (size_t)blockIdx.x * 2048;
  for (int i = t; i < 2048; i += 256) o[i] = tab[i];
}

// ---- fin pass 2: out[n] = sum/deg + t0c[n] + ind*kb + kc ----
__global__ __launch_bounds__(256) void finB(
    const float* __restrict__ partial, const float* __restrict__ t0,
    const float* __restrict__ degf, const float* __restrict__ kb,
    const float* __restrict__ kc, float* __restrict__ out) {
  int n = blockIdx.x * 256 + threadIdx.x;
  if (n >= NNODES) return;
  int b = n >> 9, i = n & 511;
  float a[4] = {0.f, 0.f, 0.f, 0.f};
#pragma unroll
  for (int s = 0; s < 8; s++) {
    const float* p = partial + (size_t)(b * 8 + s) * 2048 + i * 4;
#pragma unroll
    for (int j = 0; j < 4; j++) a[j] += p[j];
  }
  float deg = degf[n];
  float sc = (deg > 0.f) ? 1.f / deg : 0.f;
  float ind = (deg > 0.f) ? 1.f : 0.f;
  float4 c = *reinterpret_cast<const float4*>(t0 + (size_t)n * 12 + 8);
  float4 vb = *reinterpret_cast<const float4*>(kb);
  float4 vc = *reinterpret_cast<const float4*>(kc);
  float4 o = {a[0] * sc + c.x + ind * vb.x + vc.x,
              a[1] * sc + c.y + ind * vb.y + vc.y,
              a[2] * sc + c.z + ind * vb.z + vc.z,
              a[3] * sc + c.w + ind * vb.w + vc.w};
  *reinterpret_cast<float4*>(out + (size_t)n * 4) = o;
}

extern "C" void kernel_launch(void* const* d_in, const int* in_sizes, int n_in,
                              void* d_out, int out_size, void* d_ws, size_t ws_size,
                              hipStream_t stream) {
  const float* feat = (const float*)d_in[0];
  const int* ei = (const int*)d_in[1];
  const float* W_in = (const float*)d_in[3];
  const float* b_in = (const float*)d_in[4];
  const float* W1l = (const float*)d_in[5];
  const float* b1l = (const float*)d_in[6];
  const float* W1r = (const float*)d_in[7];
  const float* W2l = (const float*)d_in[8];
  const float* b2l = (const float*)d_in[9];
  const float* W2r = (const float*)d_in[10];
  const float* Wout = (const float*)d_in[11];
  const float* bout = (const float*)d_in[12];
  float* out = (float*)d_out;

  // ---- workspace layout, ~30 MB ----
  char* ws = (char*)d_ws;
  size_t off = 0;
  auto alloc = [&](size_t bytes) {
    void* p = ws + off;
    off += (bytes + 15) & ~(size_t)15;
    return p;
  };
  int* flag   = (int*)alloc(16);
  int* hist   = (int*)alloc((size_t)NBUCK * NBLK * 4);
  int* bstart = (int*)alloc((NBUCK + 1) * 4);
  unsigned int* pcol = (unsigned int*)alloc((size_t)NEDGES * 4);
  unsigned short* Wt0 = (unsigned short*)alloc(512 * 512 * 2);
  float* Wlp  = (float*)alloc(2048 * 4);
  float* Wrp  = (float*)alloc(2048 * 4);
  float* bp   = (float*)alloc(16);
  float* Pall = (float*)alloc(512 * 12 * 4);
  float* kb   = (float*)alloc(16);
  float* kc   = (float*)alloc(16);
  float* t0   = (float*)alloc((size_t)NNODES * 12 * 4);
  float* t0p  = (float*)alloc((size_t)4 * MROWS * 12 * 4);
  float* s1   = (float*)alloc((size_t)NNODES * 4 * 4);
  float* degf = (float*)alloc((size_t)NNODES * 4);
  float* partial = (float*)alloc((size_t)NBUCK * NSUB * 2560 * 4);
  (void)ws_size;

  // graph partition
  flagk<<<1, 64, 0, stream>>>(ei, flag);
  histk<<<NBLK, 256, 0, stream>>>(ei, flag, hist);
  scanh<<<1, 512, 0, stream>>>(hist, bstart);
  binscatter<<<NBLK, 256, 0, stream>>>(ei, flag, hist, pcol);

  // weight prep
  tcast<<<1024, 256, 0, stream>>>(W_in, Wt0);
  smallA<<<1025, 256, 0, stream>>>(W2l, W2r, Wout, b2l, bout, Wlp, Wrp, bp);
  smallB<<<1538, 256, 0, stream>>>(W1l, W1r, b1l, Wlp, Wrp, bp, Pall, kb, kc);

  // pipeline
  gemmproj<<<1568, 256, 0, stream>>>(feat, Wt0, b_in, Pall, t0p);
  reduce_t0<<<(NNODES * 12 + 255) / 256, 256, 0, stream>>>(t0p, t0);
  aggA<<<NBUCK * NSUB, 256, 0, stream>>>(pcol, bstart, t0, partial);
  finA<<<(NNODES + 255) / 256, 256, 0, stream>>>(partial, t0, s1, degf);
  aggB<<<NBUCK * NSUB, 256, 0, stream>>>(pcol, bstart, s1, partial);
  finB<<<(NNODES + 255) / 256, 256, 0, stream>>>(partial, t0, degf, kb, kc, out);
}

// Round 8
// 303.684 us; speedup vs baseline: 1.0084x; 1.0084x over previous
//
#include <hip/hip_runtime.h>
#include <stdint.h>

#define NNODES 50000
#define NEDGES 1600000
#define HID 512
#define NEG_SLOPE 0.01f
#define NBUCK 98     // dst>>9 buckets (512 nodes each)
#define NBLK 200     // partition blocks
#define TILE 8000    // NEDGES / NBLK
#define NSUB 8       // agg sub-blocks per bucket
#define GPBLK 391    // ceil(50000/128) M-tiles
#define MROWS 50048  // padded rows

typedef __attribute__((ext_vector_type(8))) short bf16x8;
typedef __attribute__((ext_vector_type(8))) unsigned short u16x8;
typedef __attribute__((ext_vector_type(4))) float f32x4;

__device__ __forceinline__ float bf2f(unsigned short u) {
  unsigned int x = ((unsigned int)u) << 16;
  return __builtin_bit_cast(float, x);
}
__device__ __forceinline__ unsigned short f2bf(float f) {
  unsigned int u = __builtin_bit_cast(unsigned int, f);
  u += 0x7FFFu + ((u >> 16) & 1u);
  return (unsigned short)(u >> 16);
}
__device__ __forceinline__ void gload_lds16(const void* g, void* l) {
  __builtin_amdgcn_global_load_lds(
      (const __attribute__((address_space(1))) void*)g,
      (__attribute__((address_space(3))) void*)l, 16, 0, 0);
}

// ---- detect edge_index storage (int32 vs int64-as-u32-pairs) ----
__global__ void flagk(const int* __restrict__ ei, int* __restrict__ flag) {
  int t = threadIdx.x;
  unsigned long long m = __ballot(ei[2 * t + 1] != 0);
  if (t == 0) *flag = (m != 0ULL) ? 1 : 0;
}

// ---- per-block bucket histogram: hist[b*NBLK + blk] ----
__global__ __launch_bounds__(256) void histk(const int* __restrict__ ei,
                                             const int* __restrict__ flag,
                                             int* __restrict__ hist) {
  __shared__ int h[NBUCK];
  int t = threadIdx.x, blk = blockIdx.x;
  for (int i = t; i < NBUCK; i += 256) h[i] = 0;
  __syncthreads();
  int f = *flag;
  int e0 = blk * TILE;
  for (int e = e0 + 2 * t; e < e0 + TILE; e += 512) {
    int d0, d1;
    if (f) {
      int2 v = *reinterpret_cast<const int2*>(&ei[(size_t)NEDGES + e]);
      d0 = v.x; d1 = v.y;
    } else {
      int4 v = *reinterpret_cast<const int4*>(&ei[2 * ((size_t)NEDGES + e)]);
      d0 = v.x; d1 = v.z;
    }
    if ((unsigned)d0 < NNODES) atomicAdd(&h[d0 >> 9], 1);
    if ((unsigned)d1 < NNODES) atomicAdd(&h[d1 >> 9], 1);
  }
  __syncthreads();
  for (int i = t; i < NBUCK; i += 256) hist[i * NBLK + blk] = h[i];
}

// ---- single-block exclusive scan of hist (bucket-major) -> bases + bstart ----
__global__ __launch_bounds__(512) void scanh(int* __restrict__ hist,
                                             int* __restrict__ bstart) {
  __shared__ int s[512];
  const int TOT = NBUCK * NBLK;  // 19600
  const int C = 40;
  int t = threadIdx.x;
  int base = t * C;
  int sum = 0;
#pragma unroll
  for (int i = 0; i < C; i++) {
    int idx = base + i;
    sum += (idx < TOT) ? hist[idx] : 0;
  }
  s[t] = sum;
  __syncthreads();
  for (int off = 1; off < 512; off <<= 1) {
    int u = (t >= off) ? s[t - off] : 0;
    __syncthreads();
    s[t] += u;
    __syncthreads();
  }
  int run = (t > 0) ? s[t - 1] : 0;
#pragma unroll
  for (int i = 0; i < C; i++) {
    int idx = base + i;
    if (idx < TOT) {
      int v = hist[idx];
      hist[idx] = run;
      if (idx % NBLK == 0) bstart[idx / NBLK] = run;
      run += v;
    }
  }
  if (t == 511) bstart[NBUCK] = s[511];
}

// ---- bucketed scatter: packed (dst&511)<<16 | src, LDS-local positions ----
__global__ __launch_bounds__(256) void binscatter(const int* __restrict__ ei,
                                                  const int* __restrict__ flag,
                                                  const int* __restrict__ hbase,
                                                  unsigned int* __restrict__ pcol) {
  __shared__ int lb[NBUCK];
  int t = threadIdx.x, blk = blockIdx.x;
  for (int i = t; i < NBUCK; i += 256) lb[i] = hbase[i * NBLK + blk];
  __syncthreads();
  int f = *flag;
  int e0 = blk * TILE;
  for (int e = e0 + 2 * t; e < e0 + TILE; e += 512) {
    int s0, s1, d0, d1;
    if (f) {
      int2 vs = *reinterpret_cast<const int2*>(&ei[e]);
      int2 vd = *reinterpret_cast<const int2*>(&ei[(size_t)NEDGES + e]);
      s0 = vs.x; s1 = vs.y; d0 = vd.x; d1 = vd.y;
    } else {
      int4 vs = *reinterpret_cast<const int4*>(&ei[2 * (size_t)e]);
      int4 vd = *reinterpret_cast<const int4*>(&ei[2 * ((size_t)NEDGES + e)]);
      s0 = vs.x; s1 = vs.z; d0 = vd.x; d1 = vd.z;
    }
    if ((unsigned)d0 < NNODES) {
      if ((unsigned)s0 >= NNODES) s0 = 0;
      int pos = atomicAdd(&lb[d0 >> 9], 1);
      pcol[pos] = ((unsigned)(d0 & 511) << 16) | (unsigned)s0;
    }
    if ((unsigned)d1 < NNODES) {
      if ((unsigned)s1 >= NNODES) s1 = 0;
      int pos = atomicAdd(&lb[d1 >> 9], 1);
      pcol[pos] = ((unsigned)(d1 & 511) << 16) | (unsigned)s1;
    }
  }
}

// ---- castA: featb[r][k] = bf16(feat[r][k]), rows >= NNODES zeroed ----
__global__ __launch_bounds__(256) void castA(const float* __restrict__ f,
                                             unsigned short* __restrict__ o) {
  int idx = blockIdx.x * 256 + threadIdx.x;   // over MROWS*64 groups of 8
  if (idx >= MROWS * 64) return;
  size_t g = (size_t)idx * 8;
  int row = idx >> 6;
  u16x8 pk;
  if (row < NNODES) {
    float4 v0 = *reinterpret_cast<const float4*>(f + g);
    float4 v1 = *reinterpret_cast<const float4*>(f + g + 4);
    pk[0] = f2bf(v0.x); pk[1] = f2bf(v0.y); pk[2] = f2bf(v0.z); pk[3] = f2bf(v0.w);
    pk[4] = f2bf(v1.x); pk[5] = f2bf(v1.y); pk[6] = f2bf(v1.z); pk[7] = f2bf(v1.w);
  } else {
    pk = (u16x8)0;
  }
  *reinterpret_cast<u16x8*>(o + g) = pk;
}

// ---- Wt0[n][k] = bf16(W_in[k][n]) ----
__global__ void tcast(const float* __restrict__ w, unsigned short* __restrict__ wt) {
  int i = blockIdx.x * 256 + threadIdx.x;  // 262144
  int n = i >> 9, k = i & 511;
  wt[i] = f2bf(w[(k << 9) | n]);
}

// ---- wave-parallel 512-dot ----
__device__ __forceinline__ float wave_dot(const float* __restrict__ Arow,
                                          const float* __restrict__ B, int j) {
  int l = threadIdx.x & 63;
  float4 a0 = *reinterpret_cast<const float4*>(Arow + l * 8);
  float4 a1 = *reinterpret_cast<const float4*>(Arow + l * 8 + 4);
  const float* bb = B + (size_t)(l * 8) * 4 + j;
  float s = a0.x * bb[0] + a0.y * bb[4] + a0.z * bb[8] + a0.w * bb[12] +
            a1.x * bb[16] + a1.y * bb[20] + a1.z * bb[24] + a1.w * bb[28];
#pragma unroll
  for (int off = 1; off < 64; off <<= 1) s += __shfl_xor(s, off);
  return s;
}

__global__ __launch_bounds__(256) void smallA(
    const float* __restrict__ W2l, const float* __restrict__ W2r,
    const float* __restrict__ Wout, const float* __restrict__ b2l,
    const float* __restrict__ bout,
    float* __restrict__ Wlp, float* __restrict__ Wrp, float* __restrict__ bp) {
  int gw = blockIdx.x * 4 + (threadIdx.x >> 6);
  int l = threadIdx.x & 63;
  if (gw < 2048) {
    float v = wave_dot(W2l + (size_t)(gw >> 2) * 512, Wout, gw & 3);
    if (l == 0) Wlp[gw] = v;
  } else if (gw < 4096) {
    int g = gw - 2048;
    float v = wave_dot(W2r + (size_t)(g >> 2) * 512, Wout, g & 3);
    if (l == 0) Wrp[g] = v;
  } else if (gw < 4100) {
    int j = gw - 4096;
    float v = wave_dot(b2l, Wout, j);
    if (l == 0) bp[j] = v + bout[j];
  }
}

__global__ __launch_bounds__(256) void smallB(
    const float* __restrict__ W1l, const float* __restrict__ W1r,
    const float* __restrict__ b1l,
    const float* __restrict__ Wlp, const float* __restrict__ Wrp,
    const float* __restrict__ bp,
    float* __restrict__ Pall, float* __restrict__ kb, float* __restrict__ kc) {
  int gw = blockIdx.x * 4 + (threadIdx.x >> 6);
  int l = threadIdx.x & 63;
  if (gw < 6144) {
    int k = gw / 12, jg = gw % 12;
    int g = jg >> 2, j = jg & 3;
    float v;
    if (g == 0) v = wave_dot(W1l + (size_t)k * 512, Wlp, j);
    else if (g == 1) v = wave_dot(W1r + (size_t)k * 512, Wlp, j) +
                         wave_dot(W1l + (size_t)k * 512, Wrp, j);
    else v = wave_dot(W1r + (size_t)k * 512, Wrp, j);
    if (l == 0) Pall[k * 12 + jg] = v;
  } else if (gw < 6152) {
    int i = gw - 6144, j = i & 3;
    if (i < 4) {
      float v = wave_dot(b1l, Wlp, j);
      if (l == 0) kb[j] = v;
    } else {
      float v = wave_dot(b1l, Wrp, j);
      if (l == 0) kc[j] = v + bp[j];
    }
  }
}

// ---- fused GEMM1 + 12-col projection, m97 structure, both operands via
// global_load_lds (A precast to bf16). 128x128 tile, 4 waves, N split 4-way.
// Swapped-operand MFMA: acc[ni][mi] lane holds rows (wr*64+mi*16+r15),
// cols (bn+wc*64+ni*16+kl*4+rg). Projection fp32 from acc, per-mi (12 regs).
__global__ __launch_bounds__(256, 4) void gemmproj(
    const unsigned short* __restrict__ Ab, const unsigned short* __restrict__ Bt,
    const float* __restrict__ bias, const float* __restrict__ Pall,
    float* __restrict__ t0p) {
  __shared__ unsigned short As[128 * 32];
  __shared__ unsigned short Bs[128 * 32];
  __shared__ float tab[128 * 12];
  const int tid = threadIdx.x;
  const int wave = tid >> 6, lane = tid & 63;
  // swizzle: sibling N-blocks (same mt) share XCD slot
  const int w = blockIdx.x;
  const int mt = (w & 7) + ((w >> 5) << 3);
  const int nb = (w >> 3) & 3;
  if (mt >= GPBLK) return;
  const int bm = mt * 128, bn = nb * 128;
  const int wr = wave >> 1, wc = wave & 1;
  const int r15 = lane & 15, kl = lane >> 4;
  const int srow = lane >> 2, soff = (lane & 3) * 8;

  for (int i = tid; i < 1536; i += 256) tab[i] = 0.f;

  f32x4 acc[4][4];  // [ni][mi]
#pragma unroll
  for (int i = 0; i < 4; i++)
#pragma unroll
    for (int j = 0; j < 4; j++) acc[i][j] = {0.f, 0.f, 0.f, 0.f};

  for (int kt = 0; kt < HID / 32; ++kt) {
    // A and B tiles: async global->LDS (wave-uniform LDS base + lane*16B)
#pragma unroll
    for (int rr = 0; rr < 2; ++rr) {
      int c = wave * 2 + rr;
      int row = c * 16 + srow;
      gload_lds16(Ab + (size_t)(bm + row) * HID + kt * 32 + soff, (void*)&As[c * 512]);
      gload_lds16(Bt + (size_t)(bn + row) * HID + kt * 32 + soff, (void*)&Bs[c * 512]);
    }
    __syncthreads();
    bf16x8 af[4], bfr[4];
#pragma unroll
    for (int mi = 0; mi < 4; ++mi)
      af[mi] = *reinterpret_cast<const bf16x8*>(&As[(wr * 64 + mi * 16 + r15) * 32 + kl * 8]);
#pragma unroll
    for (int ni = 0; ni < 4; ++ni)
      bfr[ni] = *reinterpret_cast<const bf16x8*>(&Bs[(wc * 64 + ni * 16 + r15) * 32 + kl * 8]);
#pragma unroll
    for (int ni = 0; ni < 4; ++ni)
#pragma unroll
      for (int mi = 0; mi < 4; ++mi)
        acc[ni][mi] = __builtin_amdgcn_mfma_f32_16x16x32_bf16(bfr[ni], af[mi], acc[ni][mi], 0, 0, 0);
    __syncthreads();
  }

  // ---- projection epilogue (fp32, per-mi to keep 12 live regs) ----
#pragma unroll
  for (int mi = 0; mi < 4; ++mi) {
    float p12[12];
#pragma unroll
    for (int j = 0; j < 12; ++j) p12[j] = 0.f;
#pragma unroll
    for (int ni = 0; ni < 4; ++ni) {
      int nbase = bn + wc * 64 + ni * 16 + kl * 4;
      float4 bv4 = *reinterpret_cast<const float4*>(bias + nbase);
      float bb[4] = {bv4.x, bv4.y, bv4.z, bv4.w};
#pragma unroll
      for (int rg = 0; rg < 4; ++rg) {
        float v = acc[ni][mi][rg] + bb[rg];
        v = (v >= 0.f) ? v : NEG_SLOPE * v;
        const float* Pc = Pall + (size_t)(nbase + rg) * 12;
        float4 p0 = *reinterpret_cast<const float4*>(Pc);
        float4 p1 = *reinterpret_cast<const float4*>(Pc + 4);
        float4 p2 = *reinterpret_cast<const float4*>(Pc + 8);
        p12[0] += v * p0.x; p12[1] += v * p0.y; p12[2] += v * p0.z; p12[3] += v * p0.w;
        p12[4] += v * p1.x; p12[5] += v * p1.y; p12[6] += v * p1.z; p12[7] += v * p1.w;
        p12[8] += v * p2.x; p12[9] += v * p2.y; p12[10] += v * p2.z; p12[11] += v * p2.w;
      }
    }
#pragma unroll
    for (int j = 0; j < 12; ++j) {
      p12[j] += __shfl_xor(p12[j], 16);
      p12[j] += __shfl_xor(p12[j], 32);
    }
    if (kl == 0) {
      int r = wr * 64 + mi * 16 + r15;
#pragma unroll
      for (int j = 0; j < 12; ++j) atomicAdd(&tab[r * 12 + j], p12[j]);
    }
  }
  __syncthreads();
  float* o = t0p + (size_t)nb * MROWS * 12 + (size_t)bm * 12;
  for (int i = tid; i < 1536; i += 256) o[i] = tab[i];
}

// ---- t0[n][12] = sum over nb partials ----
__global__ __launch_bounds__(256) void reduce_t0(const float* __restrict__ t0p,
                                                 float* __restrict__ t0) {
  int i = blockIdx.x * 256 + threadIdx.x;
  if (i >= NNODES * 12) return;
  const size_t S = (size_t)MROWS * 12;
  t0[i] = t0p[i] + t0p[S + i] + t0p[2 * S + i] + t0p[3 * S + i];
}

// ---- agg pass 1 (bucketed LDS accumulate): vals = t0a[src], + degree ----
__global__ __launch_bounds__(256) void aggA(
    const unsigned int* __restrict__ pcol, const int* __restrict__ bstart,
    const float* __restrict__ t0, float* __restrict__ partial) {
  __shared__ float tab[512 * 5];
  int t = threadIdx.x;
  int b = blockIdx.x >> 3, sb = blockIdx.x & 7;
  for (int i = t; i < 2560; i += 256) tab[i] = 0.f;
  __syncthreads();
  int st = bstart[b], en = bstart[b + 1];
  int len = en - st;
  int a0 = st + (int)(((long long)len * sb) >> 3);
  int a1 = st + (int)(((long long)len * (sb + 1)) >> 3);
  for (int e = a0 + t; e < a1; e += 256) {
    unsigned v = pcol[e];
    int i = v >> 16, src = v & 0xFFFF;
    float4 x = *reinterpret_cast<const float4*>(t0 + (size_t)src * 12);
    atomicAdd(&tab[i * 5 + 0], x.x);
    atomicAdd(&tab[i * 5 + 1], x.y);
    atomicAdd(&tab[i * 5 + 2], x.z);
    atomicAdd(&tab[i * 5 + 3], x.w);
    atomicAdd(&tab[i * 5 + 4], 1.f);
  }
  __syncthreads();
  float* o = partial + (size_t)blockIdx.x * 2560;
  for (int i = t; i < 2560; i += 256) o[i] = tab[i];
}

// ---- fin pass 1: s1[n] = sum/deg + t0b[n]; store deg ----
__global__ __launch_bounds__(256) void finA(
    const float* __restrict__ partial, const float* __restrict__ t0,
    float* __restrict__ s1, float* __restrict__ degf) {
  int n = blockIdx.x * 256 + threadIdx.x;
  if (n >= NNODES) return;
  int b = n >> 9, i = n & 511;
  float a[5] = {0.f, 0.f, 0.f, 0.f, 0.f};
#pragma unroll
  for (int s = 0; s < 8; s++) {
    const float* p = partial + (size_t)(b * 8 + s) * 2560 + i * 5;
#pragma unroll
    for (int j = 0; j < 5; j++) a[j] += p[j];
  }
  float deg = a[4];
  float sc = (deg > 0.f) ? 1.f / deg : 0.f;
  float4 tb = *reinterpret_cast<const float4*>(t0 + (size_t)n * 12 + 4);
  float4 o = {a[0] * sc + tb.x, a[1] * sc + tb.y, a[2] * sc + tb.z, a[3] * sc + tb.w};
  *reinterpret_cast<float4*>(s1 + (size_t)n * 4) = o;
  degf[n] = deg;
}

// ---- agg pass 2: vals = s1[src] ----
__global__ __launch_bounds__(256) void aggB(
    const unsigned int* __restrict__ pcol, const int* __restrict__ bstart,
    const float* __restrict__ s1, float* __restrict__ partial) {
  __shared__ float tab[512 * 4];
  int t = threadIdx.x;
  int b = blockIdx.x >> 3, sb = blockIdx.x & 7;
  for (int i = t; i < 2048; i += 256) tab[i] = 0.f;
  __syncthreads();
  int st = bstart[b], en = bstart[b + 1];
  int len = en - st;
  int a0 = st + (int)(((long long)len * sb) >> 3);
  int a1 = st + (int)(((long long)len * (sb + 1)) >> 3);
  for (int e = a0 + t; e < a1; e += 256) {
    unsigned v = pcol[e];
    int i = v >> 16, src = v & 0xFFFF;
    float4 x = *reinterpret_cast<const float4*>(s1 + (size_t)src * 4);
    atomicAdd(&tab[i * 4 + 0], x.x);
    atomicAdd(&tab[i * 4 + 1], x.y);
    atomicAdd(&tab[i * 4 + 2], x.z);
    atomicAdd(&tab[i * 4 + 3], x.w);
  }
  __syncthreads();
  float* o = partial + (size_t)blockIdx.x * 2048;
  for (int i = t; i < 2048; i += 256) o[i] = tab[i];
}

// ---- fin pass 2: out[n] = sum/deg + t0c[n] + ind*kb + kc ----
__global__ __launch_bounds__(256) void finB(
    const float* __restrict__ partial, const float* __restrict__ t0,
    const float* __restrict__ degf, const float* __restrict__ kb,
    const float* __restrict__ kc, float* __restrict__ out) {
  int n = blockIdx.x * 256 + threadIdx.x;
  if (n >= NNODES) return;
  int b = n >> 9, i = n & 511;
  float a[4] = {0.f, 0.f, 0.f, 0.f};
#pragma unroll
  for (int s = 0; s < 8; s++) {
    const float* p = partial + (size_t)(b * 8 + s) * 2048 + i * 4;
#pragma unroll
    for (int j = 0; j < 4; j++) a[j] += p[j];
  }
  float deg = degf[n];
  float sc = (deg > 0.f) ? 1.f / deg : 0.f;
  float ind = (deg > 0.f) ? 1.f : 0.f;
  float4 c = *reinterpret_cast<const float4*>(t0 + (size_t)n * 12 + 8);
  float4 vb = *reinterpret_cast<const float4*>(kb);
  float4 vc = *reinterpret_cast<const float4*>(kc);
  float4 o = {a[0] * sc + c.x + ind * vb.x + vc.x,
              a[1] * sc + c.y + ind * vb.y + vc.y,
              a[2] * sc + c.z + ind * vb.z + vc.z,
              a[3] * sc + c.w + ind * vb.w + vc.w};
  *reinterpret_cast<float4*>(out + (size_t)n * 4) = o;
}

extern "C" void kernel_launch(void* const* d_in, const int* in_sizes, int n_in,
                              void* d_out, int out_size, void* d_ws, size_t ws_size,
                              hipStream_t stream) {
  const float* feat = (const float*)d_in[0];
  const int* ei = (const int*)d_in[1];
  const float* W_in = (const float*)d_in[3];
  const float* b_in = (const float*)d_in[4];
  const float* W1l = (const float*)d_in[5];
  const float* b1l = (const float*)d_in[6];
  const float* W1r = (const float*)d_in[7];
  const float* W2l = (const float*)d_in[8];
  const float* b2l = (const float*)d_in[9];
  const float* W2r = (const float*)d_in[10];
  const float* Wout = (const float*)d_in[11];
  const float* bout = (const float*)d_in[12];
  float* out = (float*)d_out;

  // ---- workspace layout, ~81 MB ----
  char* ws = (char*)d_ws;
  size_t off = 0;
  auto alloc = [&](size_t bytes) {
    void* p = ws + off;
    off += (bytes + 15) & ~(size_t)15;
    return p;
  };
  int* flag   = (int*)alloc(16);
  int* hist   = (int*)alloc((size_t)NBUCK * NBLK * 4);
  int* bstart = (int*)alloc((NBUCK + 1) * 4);
  unsigned int* pcol = (unsigned int*)alloc((size_t)NEDGES * 4);
  unsigned short* featb = (unsigned short*)alloc((size_t)MROWS * HID * 2);
  unsigned short* Wt0 = (unsigned short*)alloc(512 * 512 * 2);
  float* Wlp  = (float*)alloc(2048 * 4);
  float* Wrp  = (float*)alloc(2048 * 4);
  float* bp   = (float*)alloc(16);
  float* Pall = (float*)alloc(512 * 12 * 4);
  float* kb   = (float*)alloc(16);
  float* kc   = (float*)alloc(16);
  float* t0   = (float*)alloc((size_t)NNODES * 12 * 4);
  float* t0p  = (float*)alloc((size_t)4 * MROWS * 12 * 4);
  float* s1   = (float*)alloc((size_t)NNODES * 4 * 4);
  float* degf = (float*)alloc((size_t)NNODES * 4);
  float* partial = (float*)alloc((size_t)NBUCK * NSUB * 2560 * 4);
  (void)ws_size;

  // graph partition
  flagk<<<1, 64, 0, stream>>>(ei, flag);
  histk<<<NBLK, 256, 0, stream>>>(ei, flag, hist);
  scanh<<<1, 512, 0, stream>>>(hist, bstart);
  binscatter<<<NBLK, 256, 0, stream>>>(ei, flag, hist, pcol);

  // weight/feature prep
  castA<<<(MROWS * 64 + 255) / 256, 256, 0, stream>>>(feat, featb);
  tcast<<<1024, 256, 0, stream>>>(W_in, Wt0);
  smallA<<<1025, 256, 0, stream>>>(W2l, W2r, Wout, b2l, bout, Wlp, Wrp, bp);
  smallB<<<1538, 256, 0, stream>>>(W1l, W1r, b1l, Wlp, Wrp, bp, Pall, kb, kc);

  // pipeline
  gemmproj<<<1568, 256, 0, stream>>>(featb, Wt0, b_in, Pall, t0p);
  reduce_t0<<<(NNODES * 12 + 255) / 256, 256, 0, stream>>>(t0p, t0);
  aggA<<<NBUCK * NSUB, 256, 0, stream>>>(pcol, bstart, t0, partial);
  finA<<<(NNODES + 255) / 256, 256, 0, stream>>>(partial, t0, s1, degf);
  aggB<<<NBUCK * NSUB, 256, 0, stream>>>(pcol, bstart, s1, partial);
  finB<<<(NNODES + 255) / 256, 256, 0, stream>>>(partial, t0, degf, kb, kc, out);
}

// Round 9
// 289.088 us; speedup vs baseline: 1.0594x; 1.0505x over previous
//
#include <hip/hip_runtime.h>
#include <stdint.h>

#define NNODES 50000
#define NEDGES 1600000
#define HID 512
#define NEG_SLOPE 0.01f
#define NBUCK 98     // dst>>9 buckets (512 nodes each)
#define NBLK 200     // partition blocks
#define TILE 8000    // NEDGES / NBLK
#define NSUB 8       // agg sub-blocks per bucket
#define GPBLK 391    // ceil(50000/128) M-tiles
#define MROWS 50048  // padded rows

// prep kernel block ranges
#define ZTOT4 263040        // float4s to zero: (3*MROWS*4 + NBUCK*2560 + NBUCK*2048)/4
#define ZBLK 1028
#define TCBLK 1024
#define CABLK 12512         // MROWS*64/256
#define SABLK 1025
#define PREP_TC (ZBLK)
#define PREP_CA (ZBLK + TCBLK)
#define PREP_SA (ZBLK + TCBLK + CABLK)
#define PREP_FLAG (ZBLK + TCBLK + CABLK + SABLK)
#define PREP_GRID (PREP_FLAG + 1)

typedef __attribute__((ext_vector_type(8))) short bf16x8;
typedef __attribute__((ext_vector_type(8))) unsigned short u16x8;
typedef __attribute__((ext_vector_type(4))) float f32x4;

__device__ __forceinline__ unsigned short f2bf(float f) {
  unsigned int u = __builtin_bit_cast(unsigned int, f);
  u += 0x7FFFu + ((u >> 16) & 1u);
  return (unsigned short)(u >> 16);
}
__device__ __forceinline__ void gload_lds16(const void* g, void* l) {
  __builtin_amdgcn_global_load_lds(
      (const __attribute__((address_space(1))) void*)g,
      (__attribute__((address_space(3))) void*)l, 16, 0, 0);
}

// ---- wave-parallel 512-dot ----
__device__ __forceinline__ float wave_dot(const float* __restrict__ Arow,
                                          const float* __restrict__ B, int j) {
  int l = threadIdx.x & 63;
  float4 a0 = *reinterpret_cast<const float4*>(Arow + l * 8);
  float4 a1 = *reinterpret_cast<const float4*>(Arow + l * 8 + 4);
  const float* bb = B + (size_t)(l * 8) * 4 + j;
  float s = a0.x * bb[0] + a0.y * bb[4] + a0.z * bb[8] + a0.w * bb[12] +
            a1.x * bb[16] + a1.y * bb[20] + a1.z * bb[24] + a1.w * bb[28];
#pragma unroll
  for (int off = 1; off < 64; off <<= 1) s += __shfl_xor(s, off);
  return s;
}

// ---- prep: zero accumulators | tcast | castA | smallA | flag ----
__global__ __launch_bounds__(256) void prep(
    const float* __restrict__ feat, const float* __restrict__ W_in,
    const float* __restrict__ W2l, const float* __restrict__ W2r,
    const float* __restrict__ Wout, const float* __restrict__ b2l,
    const float* __restrict__ bout, const int* __restrict__ ei,
    float* __restrict__ zbase, unsigned short* __restrict__ Wt0,
    unsigned short* __restrict__ featb,
    float* __restrict__ Wlp, float* __restrict__ Wrp, float* __restrict__ bp,
    int* __restrict__ flag) {
  int blk = blockIdx.x, t = threadIdx.x;
  if (blk < PREP_TC) {
    int idx = blk * 256 + t;
    if (idx < ZTOT4) reinterpret_cast<float4*>(zbase)[idx] = {0.f, 0.f, 0.f, 0.f};
  } else if (blk < PREP_CA) {
    int i = (blk - PREP_TC) * 256 + t;  // 262144
    int n = i >> 9, k = i & 511;
    Wt0[i] = f2bf(W_in[(k << 9) | n]);
  } else if (blk < PREP_SA) {
    int idx = (blk - PREP_CA) * 256 + t;  // over MROWS*64 groups of 8
    size_t g = (size_t)idx * 8;
    int row = idx >> 6;
    u16x8 pk;
    if (row < NNODES) {
      float4 v0 = *reinterpret_cast<const float4*>(feat + g);
      float4 v1 = *reinterpret_cast<const float4*>(feat + g + 4);
      pk[0] = f2bf(v0.x); pk[1] = f2bf(v0.y); pk[2] = f2bf(v0.z); pk[3] = f2bf(v0.w);
      pk[4] = f2bf(v1.x); pk[5] = f2bf(v1.y); pk[6] = f2bf(v1.z); pk[7] = f2bf(v1.w);
    } else {
      pk = (u16x8)0;
    }
    *reinterpret_cast<u16x8*>(featb + g) = pk;
  } else if (blk < PREP_FLAG) {
    int gw = (blk - PREP_SA) * 4 + (t >> 6);
    int l = t & 63;
    if (gw < 2048) {
      float v = wave_dot(W2l + (size_t)(gw >> 2) * 512, Wout, gw & 3);
      if (l == 0) Wlp[gw] = v;
    } else if (gw < 4096) {
      int g = gw - 2048;
      float v = wave_dot(W2r + (size_t)(g >> 2) * 512, Wout, g & 3);
      if (l == 0) Wrp[g] = v;
    } else if (gw < 4100) {
      int j = gw - 4096;
      float v = wave_dot(b2l, Wout, j);
      if (l == 0) bp[j] = v + bout[j];
    }
  } else {
    if (t < 64) {
      unsigned long long m = __ballot(ei[2 * t + 1] != 0);
      if (t == 0) *flag = (m != 0ULL) ? 1 : 0;
    }
  }
}

// ---- smallB: Pall folds (needs Wlp/Wrp/bp from prep) ----
__global__ __launch_bounds__(256) void smallB(
    const float* __restrict__ W1l, const float* __restrict__ W1r,
    const float* __restrict__ b1l,
    const float* __restrict__ Wlp, const float* __restrict__ Wrp,
    const float* __restrict__ bp,
    float* __restrict__ Pall, float* __restrict__ kb, float* __restrict__ kc) {
  int gw = blockIdx.x * 4 + (threadIdx.x >> 6);
  int l = threadIdx.x & 63;
  if (gw < 6144) {
    int k = gw / 12, jg = gw % 12;
    int g = jg >> 2, j = jg & 3;
    float v;
    if (g == 0) v = wave_dot(W1l + (size_t)k * 512, Wlp, j);
    else if (g == 1) v = wave_dot(W1r + (size_t)k * 512, Wlp, j) +
                         wave_dot(W1l + (size_t)k * 512, Wrp, j);
    else v = wave_dot(W1r + (size_t)k * 512, Wrp, j);
    if (l == 0) Pall[k * 12 + jg] = v;
  } else if (gw < 6152) {
    int i = gw - 6144, j = i & 3;
    if (i < 4) {
      float v = wave_dot(b1l, Wlp, j);
      if (l == 0) kb[j] = v;
    } else {
      float v = wave_dot(b1l, Wrp, j);
      if (l == 0) kc[j] = v + bp[j];
    }
  }
}

// ---- per-block bucket histogram ----
__global__ __launch_bounds__(256) void histk(const int* __restrict__ ei,
                                             const int* __restrict__ flag,
                                             int* __restrict__ hist) {
  __shared__ int h[NBUCK];
  int t = threadIdx.x, blk = blockIdx.x;
  for (int i = t; i < NBUCK; i += 256) h[i] = 0;
  __syncthreads();
  int f = *flag;
  int e0 = blk * TILE;
  for (int e = e0 + 2 * t; e < e0 + TILE; e += 512) {
    int d0, d1;
    if (f) {
      int2 v = *reinterpret_cast<const int2*>(&ei[(size_t)NEDGES + e]);
      d0 = v.x; d1 = v.y;
    } else {
      int4 v = *reinterpret_cast<const int4*>(&ei[2 * ((size_t)NEDGES + e)]);
      d0 = v.x; d1 = v.z;
    }
    if ((unsigned)d0 < NNODES) atomicAdd(&h[d0 >> 9], 1);
    if ((unsigned)d1 < NNODES) atomicAdd(&h[d1 >> 9], 1);
  }
  __syncthreads();
  for (int i = t; i < NBUCK; i += 256) hist[i * NBLK + blk] = h[i];
}

// ---- single-block exclusive scan of hist ----
__global__ __launch_bounds__(512) void scanh(int* __restrict__ hist,
                                             int* __restrict__ bstart) {
  __shared__ int s[512];
  const int TOT = NBUCK * NBLK;  // 19600
  const int C = 40;
  int t = threadIdx.x;
  int base = t * C;
  int sum = 0;
#pragma unroll
  for (int i = 0; i < C; i++) {
    int idx = base + i;
    sum += (idx < TOT) ? hist[idx] : 0;
  }
  s[t] = sum;
  __syncthreads();
  for (int off = 1; off < 512; off <<= 1) {
    int u = (t >= off) ? s[t - off] : 0;
    __syncthreads();
    s[t] += u;
    __syncthreads();
  }
  int run = (t > 0) ? s[t - 1] : 0;
#pragma unroll
  for (int i = 0; i < C; i++) {
    int idx = base + i;
    if (idx < TOT) {
      int v = hist[idx];
      hist[idx] = run;
      if (idx % NBLK == 0) bstart[idx / NBLK] = run;
      run += v;
    }
  }
  if (t == 511) bstart[NBUCK] = s[511];
}

// ---- bucketed scatter: packed (dst&511)<<16 | src ----
__global__ __launch_bounds__(256) void binscatter(const int* __restrict__ ei,
                                                  const int* __restrict__ flag,
                                                  const int* __restrict__ hbase,
                                                  unsigned int* __restrict__ pcol) {
  __shared__ int lb[NBUCK];
  int t = threadIdx.x, blk = blockIdx.x;
  for (int i = t; i < NBUCK; i += 256) lb[i] = hbase[i * NBLK + blk];
  __syncthreads();
  int f = *flag;
  int e0 = blk * TILE;
  for (int e = e0 + 2 * t; e < e0 + TILE; e += 512) {
    int s0, s1v, d0, d1;
    if (f) {
      int2 vs = *reinterpret_cast<const int2*>(&ei[e]);
      int2 vd = *reinterpret_cast<const int2*>(&ei[(size_t)NEDGES + e]);
      s0 = vs.x; s1v = vs.y; d0 = vd.x; d1 = vd.y;
    } else {
      int4 vs = *reinterpret_cast<const int4*>(&ei[2 * (size_t)e]);
      int4 vd = *reinterpret_cast<const int4*>(&ei[2 * ((size_t)NEDGES + e)]);
      s0 = vs.x; s1v = vs.z; d0 = vd.x; d1 = vd.z;
    }
    if ((unsigned)d0 < NNODES) {
      if ((unsigned)s0 >= NNODES) s0 = 0;
      int pos = atomicAdd(&lb[d0 >> 9], 1);
      pcol[pos] = ((unsigned)(d0 & 511) << 16) | (unsigned)s0;
    }
    if ((unsigned)d1 < NNODES) {
      if ((unsigned)s1v >= NNODES) s1v = 0;
      int pos = atomicAdd(&lb[d1 >> 9], 1);
      pcol[pos] = ((unsigned)(d1 & 511) << 16) | (unsigned)s1v;
    }
  }
}

// ---- fused GEMM1 + 12-col projection, 2-phase double-buffered pipeline ----
// stage(kt+1) issued BEFORE compute(kt); ONE barrier per K-step (its implicit
// vmcnt/lgkm drain lands after compute so load latency hides under MFMA).
// Epilogue atomically adds into split t0a/t0b/t0c.
__global__ __launch_bounds__(256, 4) void gemmproj(
    const unsigned short* __restrict__ Ab, const unsigned short* __restrict__ Bt,
    const float* __restrict__ bias, const float* __restrict__ Pall,
    float* __restrict__ t0a, float* __restrict__ t0b, float* __restrict__ t0c) {
  __shared__ unsigned short As[2][128 * 32];
  __shared__ unsigned short Bs[2][128 * 32];
  __shared__ float tab[128 * 12];
  const int tid = threadIdx.x;
  const int wave = tid >> 6, lane = tid & 63;
  const int w = blockIdx.x;
  const int mt = (w & 7) + ((w >> 5) << 3);
  const int nb = (w >> 3) & 3;
  if (mt >= GPBLK) return;
  const int bm = mt * 128, bn = nb * 128;
  const int wr = wave >> 1, wc = wave & 1;
  const int r15 = lane & 15, kl = lane >> 4;
  const int srow = lane >> 2, soff = (lane & 3) * 8;
  const int c0 = wave * 2, c1 = wave * 2 + 1;
  const unsigned short* ga0 = Ab + (size_t)(bm + c0 * 16 + srow) * HID + soff;
  const unsigned short* ga1 = Ab + (size_t)(bm + c1 * 16 + srow) * HID + soff;
  const unsigned short* gb0 = Bt + (size_t)(bn + c0 * 16 + srow) * HID + soff;
  const unsigned short* gb1 = Bt + (size_t)(bn + c1 * 16 + srow) * HID + soff;

  for (int i = tid; i < 1536; i += 256) tab[i] = 0.f;

  f32x4 acc[4][4];  // [ni][mi]
#pragma unroll
  for (int i = 0; i < 4; i++)
#pragma unroll
    for (int j = 0; j < 4; j++) acc[i][j] = {0.f, 0.f, 0.f, 0.f};

  // prologue: stage kt=0 into buf 0
  gload_lds16(ga0, (void*)&As[0][c0 * 512]);
  gload_lds16(gb0, (void*)&Bs[0][c0 * 512]);
  gload_lds16(ga1, (void*)&As[0][c1 * 512]);
  gload_lds16(gb1, (void*)&Bs[0][c1 * 512]);
  __syncthreads();

  for (int kt = 0; kt < 16; ++kt) {
    const int cur = kt & 1;
    if (kt < 15) {
      const int nxt = cur ^ 1;
      const int ko = (kt + 1) * 32;
      gload_lds16(ga0 + ko, (void*)&As[nxt][c0 * 512]);
      gload_lds16(gb0 + ko, (void*)&Bs[nxt][c0 * 512]);
      gload_lds16(ga1 + ko, (void*)&As[nxt][c1 * 512]);
      gload_lds16(gb1 + ko, (void*)&Bs[nxt][c1 * 512]);
    }
    bf16x8 af[4], bfr[4];
#pragma unroll
    for (int mi = 0; mi < 4; ++mi)
      af[mi] = *reinterpret_cast<const bf16x8*>(&As[cur][(wr * 64 + mi * 16 + r15) * 32 + kl * 8]);
#pragma unroll
    for (int ni = 0; ni < 4; ++ni)
      bfr[ni] = *reinterpret_cast<const bf16x8*>(&Bs[cur][(wc * 64 + ni * 16 + r15) * 32 + kl * 8]);
#pragma unroll
    for (int ni = 0; ni < 4; ++ni)
#pragma unroll
      for (int mi = 0; mi < 4; ++mi)
        acc[ni][mi] = __builtin_amdgcn_mfma_f32_16x16x32_bf16(bfr[ni], af[mi], acc[ni][mi], 0, 0, 0);
    __syncthreads();
  }

  // ---- projection epilogue (fp32, per-mi) ----
#pragma unroll
  for (int mi = 0; mi < 4; ++mi) {
    float p12[12];
#pragma unroll
    for (int j = 0; j < 12; ++j) p12[j] = 0.f;
#pragma unroll
    for (int ni = 0; ni < 4; ++ni) {
      int nbase = bn + wc * 64 + ni * 16 + kl * 4;
      float4 bv4 = *reinterpret_cast<const float4*>(bias + nbase);
      float bb[4] = {bv4.x, bv4.y, bv4.z, bv4.w};
#pragma unroll
      for (int rg = 0; rg < 4; ++rg) {
        float v = acc[ni][mi][rg] + bb[rg];
        v = (v >= 0.f) ? v : NEG_SLOPE * v;
        const float* Pc = Pall + (size_t)(nbase + rg) * 12;
        float4 p0 = *reinterpret_cast<const float4*>(Pc);
        float4 p1 = *reinterpret_cast<const float4*>(Pc + 4);
        float4 p2 = *reinterpret_cast<const float4*>(Pc + 8);
        p12[0] += v * p0.x; p12[1] += v * p0.y; p12[2] += v * p0.z; p12[3] += v * p0.w;
        p12[4] += v * p1.x; p12[5] += v * p1.y; p12[6] += v * p1.z; p12[7] += v * p1.w;
        p12[8] += v * p2.x; p12[9] += v * p2.y; p12[10] += v * p2.z; p12[11] += v * p2.w;
      }
    }
#pragma unroll
    for (int j = 0; j < 12; ++j) {
      p12[j] += __shfl_xor(p12[j], 16);
      p12[j] += __shfl_xor(p12[j], 32);
    }
    if (kl == 0) {
      int r = wr * 64 + mi * 16 + r15;
#pragma unroll
      for (int j = 0; j < 12; ++j) atomicAdd(&tab[r * 12 + j], p12[j]);
    }
  }
  __syncthreads();
  // atomic-add tab into split global t0 arrays
  for (int i = tid; i < 1536; i += 256) {
    int r = i / 12, j = i - r * 12;
    size_t gr = (size_t)(bm + r);
    float v = tab[i];
    if (j < 4) atomicAdd(&t0a[gr * 4 + j], v);
    else if (j < 8) atomicAdd(&t0b[gr * 4 + (j - 4)], v);
    else atomicAdd(&t0c[gr * 4 + (j - 8)], v);
  }
}

// ---- agg pass 1: LDS accumulate t0a[src] + degree, atomic into accA[n*5] ----
__global__ __launch_bounds__(256) void aggA(
    const unsigned int* __restrict__ pcol, const int* __restrict__ bstart,
    const float* __restrict__ t0a, float* __restrict__ accA) {
  __shared__ float tab[512 * 5];
  int t = threadIdx.x;
  int b = blockIdx.x >> 3, sb = blockIdx.x & 7;
  for (int i = t; i < 2560; i += 256) tab[i] = 0.f;
  __syncthreads();
  int st = bstart[b], en = bstart[b + 1];
  int len = en - st;
  int a0 = st + (int)(((long long)len * sb) >> 3);
  int a1 = st + (int)(((long long)len * (sb + 1)) >> 3);
  for (int e = a0 + t; e < a1; e += 256) {
    unsigned v = pcol[e];
    int i = v >> 16, src = v & 0xFFFF;
    float4 x = *reinterpret_cast<const float4*>(t0a + (size_t)src * 4);
    atomicAdd(&tab[i * 5 + 0], x.x);
    atomicAdd(&tab[i * 5 + 1], x.y);
    atomicAdd(&tab[i * 5 + 2], x.z);
    atomicAdd(&tab[i * 5 + 3], x.w);
    atomicAdd(&tab[i * 5 + 4], 1.f);
  }
  __syncthreads();
  float* o = accA + (size_t)b * 2560;
  for (int i = t; i < 2560; i += 256) {
    float v = tab[i];
    if (v != 0.f) atomicAdd(&o[i], v);
  }
}

// ---- fin pass 1: s1[n] = sum/deg + t0b[n]; store deg ----
__global__ __launch_bounds__(256) void finA(
    const float* __restrict__ accA, const float* __restrict__ t0b,
    float* __restrict__ s1, float* __restrict__ degf) {
  int n = blockIdx.x * 256 + threadIdx.x;
  if (n >= NNODES) return;
  const float* a = accA + (size_t)n * 5;
  float deg = a[4];
  float sc = (deg > 0.f) ? 1.f / deg : 0.f;
  float4 tb = *reinterpret_cast<const float4*>(t0b + (size_t)n * 4);
  float4 o = {a[0] * sc + tb.x, a[1] * sc + tb.y, a[2] * sc + tb.z, a[3] * sc + tb.w};
  *reinterpret_cast<float4*>(s1 + (size_t)n * 4) = o;
  degf[n] = deg;
}

// ---- agg pass 2: LDS accumulate s1[src], atomic into accB[n*4] ----
__global__ __launch_bounds__(256) void aggB(
    const unsigned int* __restrict__ pcol, const int* __restrict__ bstart,
    const float* __restrict__ s1, float* __restrict__ accB) {
  __shared__ float tab[512 * 4];
  int t = threadIdx.x;
  int b = blockIdx.x >> 3, sb = blockIdx.x & 7;
  for (int i = t; i < 2048; i += 256) tab[i] = 0.f;
  __syncthreads();
  int st = bstart[b], en = bstart[b + 1];
  int len = en - st;
  int a0 = st + (int)(((long long)len * sb) >> 3);
  int a1 = st + (int)(((long long)len * (sb + 1)) >> 3);
  for (int e = a0 + t; e < a1; e += 256) {
    unsigned v = pcol[e];
    int i = v >> 16, src = v & 0xFFFF;
    float4 x = *reinterpret_cast<const float4*>(s1 + (size_t)src * 4);
    atomicAdd(&tab[i * 4 + 0], x.x);
    atomicAdd(&tab[i * 4 + 1], x.y);
    atomicAdd(&tab[i * 4 + 2], x.z);
    atomicAdd(&tab[i * 4 + 3], x.w);
  }
  __syncthreads();
  float* o = accB + (size_t)b * 2048;
  for (int i = t; i < 2048; i += 256) {
    float v = tab[i];
    if (v != 0.f) atomicAdd(&o[i], v);
  }
}

// ---- fin pass 2: out[n] = sum/deg + t0c[n] + ind*kb + kc ----
__global__ __launch_bounds__(256) void finB(
    const float* __restrict__ accB, const float* __restrict__ t0c,
    const float* __restrict__ degf, const float* __restrict__ kb,
    const float* __restrict__ kc, float* __restrict__ out) {
  int n = blockIdx.x * 256 + threadIdx.x;
  if (n >= NNODES) return;
  const float* a = accB + (size_t)n * 4;
  float deg = degf[n];
  float sc = (deg > 0.f) ? 1.f / deg : 0.f;
  float ind = (deg > 0.f) ? 1.f : 0.f;
  float4 c = *reinterpret_cast<const float4*>(t0c + (size_t)n * 4);
  float4 vb = *reinterpret_cast<const float4*>(kb);
  float4 vc = *reinterpret_cast<const float4*>(kc);
  float4 o = {a[0] * sc + c.x + ind * vb.x + vc.x,
              a[1] * sc + c.y + ind * vb.y + vc.y,
              a[2] * sc + c.z + ind * vb.z + vc.z,
              a[3] * sc + c.w + ind * vb.w + vc.w};
  *reinterpret_cast<float4*>(out + (size_t)n * 4) = o;
}

extern "C" void kernel_launch(void* const* d_in, const int* in_sizes, int n_in,
                              void* d_out, int out_size, void* d_ws, size_t ws_size,
                              hipStream_t stream) {
  const float* feat = (const float*)d_in[0];
  const int* ei = (const int*)d_in[1];
  const float* W_in = (const float*)d_in[3];
  const float* b_in = (const float*)d_in[4];
  const float* W1l = (const float*)d_in[5];
  const float* b1l = (const float*)d_in[6];
  const float* W1r = (const float*)d_in[7];
  const float* W2l = (const float*)d_in[8];
  const float* b2l = (const float*)d_in[9];
  const float* W2r = (const float*)d_in[10];
  const float* Wout = (const float*)d_in[11];
  const float* bout = (const float*)d_in[12];
  float* out = (float*)d_out;

  // ---- workspace layout ----
  char* ws = (char*)d_ws;
  size_t off = 0;
  auto alloc = [&](size_t bytes) {
    void* p = ws + off;
    off += (bytes + 15) & ~(size_t)15;
    return p;
  };
  // zero-region (contiguous, zeroed by prep): t0a|t0b|t0c|accA|accB
  float* t0a  = (float*)alloc((size_t)MROWS * 4 * 4);        // 800768 B
  float* t0b  = (float*)alloc((size_t)MROWS * 4 * 4);
  float* t0c  = (float*)alloc((size_t)MROWS * 4 * 4);
  float* accA = (float*)alloc((size_t)NBUCK * 2560 * 4);     // 1003520 B
  float* accB = (float*)alloc((size_t)NBUCK * 2048 * 4);     // 802816 B
  float* zbase = t0a;  // total 1052160 floats = ZTOT4*4

  int* flag   = (int*)alloc(16);
  int* hist   = (int*)alloc((size_t)NBUCK * NBLK * 4);
  int* bstart = (int*)alloc((NBUCK + 1) * 4);
  unsigned int* pcol = (unsigned int*)alloc((size_t)NEDGES * 4);
  unsigned short* featb = (unsigned short*)alloc((size_t)MROWS * HID * 2);
  unsigned short* Wt0 = (unsigned short*)alloc(512 * 512 * 2);
  float* Wlp  = (float*)alloc(2048 * 4);
  float* Wrp  = (float*)alloc(2048 * 4);
  float* bp   = (float*)alloc(16);
  float* Pall = (float*)alloc(512 * 12 * 4);
  float* kb   = (float*)alloc(16);
  float* kc   = (float*)alloc(16);
  float* s1   = (float*)alloc((size_t)MROWS * 4 * 4);
  float* degf = (float*)alloc((size_t)NNODES * 4);
  (void)ws_size;

  // prep: zero + tcast + castA + smallA + flag (one launch)
  prep<<<PREP_GRID, 256, 0, stream>>>(feat, W_in, W2l, W2r, Wout, b2l, bout, ei,
                                      zbase, Wt0, featb, Wlp, Wrp, bp, flag);
  smallB<<<1538, 256, 0, stream>>>(W1l, W1r, b1l, Wlp, Wrp, bp, Pall, kb, kc);

  // graph partition
  histk<<<NBLK, 256, 0, stream>>>(ei, flag, hist);
  scanh<<<1, 512, 0, stream>>>(hist, bstart);
  binscatter<<<NBLK, 256, 0, stream>>>(ei, flag, hist, pcol);

  // pipeline
  gemmproj<<<1568, 256, 0, stream>>>(featb, Wt0, b_in, Pall, t0a, t0b, t0c);
  aggA<<<NBUCK * NSUB, 256, 0, stream>>>(pcol, bstart, t0a, accA);
  finA<<<(NNODES + 255) / 256, 256, 0, stream>>>(accA, t0b, s1, degf);
  aggB<<<NBUCK * NSUB, 256, 0, stream>>>(pcol, bstart, s1, accB);
  finB<<<(NNODES + 255) / 256, 256, 0, stream>>>(accB, t0c, degf, kb, kc, out);
}